// Round 4
// baseline (310.829 us; speedup 1.0000x reference)
//
#include <hip/hip_runtime.h>
#include <hip/hip_bf16.h>

#define NT 4096
#define HD 2048
#define NE 16
#define ID 512
#define TWO_I 1024
#define PITCH 72   // LDS row pitch in ushorts (144B) -> dodges pow2 bank stride
#define MAXITEMS 47  // worst case: ceil(4081/128)=32 + 15 singleton experts

typedef __attribute__((ext_vector_type(8))) short bf16x8_t;
typedef __attribute__((ext_vector_type(4))) float f32x4_t;

__device__ __forceinline__ unsigned short f2bf(float f) {
  union { float f; unsigned int u; } v; v.f = f;
  unsigned int r = v.u + 0x7fffu + ((v.u >> 16) & 1u);
  return (unsigned short)(r >> 16);
}

// ---------------- cast x (f32 -> bf16), 8 elems/thread ----------------
__global__ void k_cast_x(const float* __restrict__ x, unsigned short* __restrict__ xb) {
  size_t i = ((size_t)blockIdx.x * 256 + threadIdx.x) * 8;
  float4 a = *(const float4*)(x + i);
  float4 b = *(const float4*)(x + i + 4);
  unsigned int w0 = (unsigned)f2bf(a.x) | ((unsigned)f2bf(a.y) << 16);
  unsigned int w1 = (unsigned)f2bf(a.z) | ((unsigned)f2bf(a.w) << 16);
  unsigned int w2 = (unsigned)f2bf(b.x) | ((unsigned)f2bf(b.y) << 16);
  unsigned int w3 = (unsigned)f2bf(b.z) | ((unsigned)f2bf(b.w) << 16);
  uint4 pk; pk.x = w0; pk.y = w1; pk.z = w2; pk.w = w3;
  *(uint4*)(xb + i) = pk;
}

// ---------------- routing ----------------
__global__ void k_route(const float* __restrict__ mu, const int* __restrict__ tok,
                        const float* __restrict__ wr, int* __restrict__ eid) {
  int t = blockIdx.x;
  int tid = threadIdx.x;
  float p[NE];
#pragma unroll
  for (int e = 0; e < NE; ++e) p[e] = 0.f;
  const float* m = mu + (size_t)t * HD;
  for (int h = tid; h < HD; h += 256) {
    float mv = m[h];
#pragma unroll
    for (int e = 0; e < NE; ++e) p[e] += mv * wr[e * HD + h];
  }
#pragma unroll
  for (int e = 0; e < NE; ++e) {
    float v = p[e];
#pragma unroll
    for (int s = 32; s; s >>= 1) v += __shfl_xor(v, s, 64);
    p[e] = v;
  }
  __shared__ float red[4][NE];
  int lane = tid & 63, wv = tid >> 6;
  if (lane == 0) {
#pragma unroll
    for (int e = 0; e < NE; ++e) red[wv][e] = p[e];
  }
  __syncthreads();
  if (tid == 0) {
    int tk = tok[t];
    if (tk < 0) tk = 0;
    if (tk > 31999) tk = 31999;
    int base = tk & 15;
    float best = -3.0e38f; int bi = 0;
    for (int e = 0; e < NE; ++e) {
      float v = red[0][e] + red[1][e] + red[2][e] + red[3][e];
      if (e == base) v += 10.0f;
      if (v > best) { best = v; bi = e; }
    }
    eid[t] = bi;
  }
}

// ---------------- bucket tokens by expert + build compacted worklist ----------------
__global__ void k_init(int* counts, int* cursors) {
  int i = threadIdx.x;
  if (i < NE) { counts[i] = 0; cursors[i] = 0; }
}
__global__ void k_hist(const int* __restrict__ eid, int* __restrict__ counts) {
  int t = blockIdx.x * 256 + threadIdx.x;
  if (t < NT) atomicAdd(&counts[eid[t]], 1);
}
__global__ void k_scan(const int* __restrict__ counts, int* __restrict__ offsets,
                       int* __restrict__ cursors, int* __restrict__ wk) {
  if (threadIdx.x == 0) {
    int s = 0;
    for (int e = 0; e < NE; ++e) { offsets[e] = s; cursors[e] = s; s += counts[e]; }
    offsets[NE] = s;
    int n = 0;
    for (int e = 0; e < NE; ++e) {
      int tiles = (counts[e] + 127) >> 7;
      for (int m = 0; m < tiles; ++m) { wk[n++] = e | (m << 8); }
    }
    wk[MAXITEMS] = n;
  }
}
__global__ void k_scatter(const int* __restrict__ eid, int* __restrict__ cursors,
                          int* __restrict__ tlist) {
  int t = blockIdx.x * 256 + threadIdx.x;
  if (t < NT) {
    int e = eid[t];
    int pos = atomicAdd(&cursors[e], 1);
    tlist[pos] = t;
  }
}

// ---------------- gemm1: h = silu(x@Wg) * (x@Wu) ----------------
// dbuf LDS; loads for step k+1 issued AFTER the barrier so they fly under MFMA(k)
__global__ __launch_bounds__(256) void k_gemm1(
    const unsigned short* __restrict__ xb, const float* __restrict__ gup,
    const int* __restrict__ offsets, const int* __restrict__ tlist,
    const int* __restrict__ wk, unsigned short* __restrict__ hbuf) {
  int item = blockIdx.y;
  if (item >= wk[MAXITEMS]) return;
  int w = wk[item];
  int e = w & 255, tb = (w >> 8) * 128;
  int off = offsets[e], cnt = offsets[e + 1] - off;
  int c0 = blockIdx.x * 64;

  __shared__ unsigned short lA[2][128 * PITCH];
  __shared__ unsigned short lB[2][128 * PITCH];
  __shared__ int ltok[128];

  int tid = threadIdx.x, lane = tid & 63, wv = tid >> 6;
  if (tid < 128) {
    int r = tb + tid; if (r > cnt - 1) r = cnt - 1;
    ltok[tid] = tlist[off + r];
  }
  __syncthreads();

  const float* Wg = gup + (size_t)e * HD * TWO_I;

  int rowA[4], octA[4], colB[4], koctB[4];
  const unsigned short* aP[4];
  const float* bP[4];
#pragma unroll
  for (int it = 0; it < 4; ++it) {
    int id = tid + 256 * it;
    rowA[it] = id >> 3; octA[it] = id & 7;
    aP[it] = xb + (size_t)ltok[rowA[it]] * HD + octA[it] * 8;
    int col = id & 127, koct = id >> 7;
    colB[it] = col; koctB[it] = koct;
    int gcol = (col < 64) ? (c0 + col) : (ID + c0 + (col - 64));
    bP[it] = Wg + (size_t)koct * 8 * TWO_I + gcol;
  }

  uint4 aR[4];
  float bR[4][8];

#define G1_ISSUE() do { \
  _Pragma("unroll") for (int it = 0; it < 4; ++it) { aR[it] = *(const uint4*)aP[it]; aP[it] += 64; } \
  _Pragma("unroll") for (int it = 0; it < 4; ++it) { \
    const float* s = bP[it]; \
    _Pragma("unroll") for (int j = 0; j < 8; ++j) bR[it][j] = s[(size_t)j * TWO_I]; \
    bP[it] += (size_t)64 * TWO_I; } \
} while (0)

  G1_ISSUE();

  f32x4_t zero = {0.f, 0.f, 0.f, 0.f};
  f32x4_t accg[2][4], accu[2][4];
#pragma unroll
  for (int m = 0; m < 2; ++m)
#pragma unroll
    for (int n = 0; n < 4; ++n) { accg[m][n] = zero; accu[m][n] = zero; }

  for (int kt = 0; kt < 32; ++kt) {
    unsigned short* A = &lA[kt & 1][0];
    unsigned short* B = &lB[kt & 1][0];
#pragma unroll
    for (int it = 0; it < 4; ++it)
      *(uint4*)&A[rowA[it] * PITCH + octA[it] * 8] = aR[it];
#pragma unroll
    for (int it = 0; it < 4; ++it) {
      uint4 pk;
      pk.x = (unsigned)f2bf(bR[it][0]) | ((unsigned)f2bf(bR[it][1]) << 16);
      pk.y = (unsigned)f2bf(bR[it][2]) | ((unsigned)f2bf(bR[it][3]) << 16);
      pk.z = (unsigned)f2bf(bR[it][4]) | ((unsigned)f2bf(bR[it][5]) << 16);
      pk.w = (unsigned)f2bf(bR[it][6]) | ((unsigned)f2bf(bR[it][7]) << 16);
      *(uint4*)&B[colB[it] * PITCH + koctB[it] * 8] = pk;
    }
    __syncthreads();
    if (kt < 31) G1_ISSUE();   // issue AFTER barrier: loads fly under MFMA phase

    int mb = wv * 32, lr = lane & 15;
#pragma unroll
    for (int kk = 0; kk < 2; ++kk) {
      int klo = kk * 32 + 8 * (lane >> 4);
      bf16x8_t a[2], bg[4], bu[4];
#pragma unroll
      for (int m = 0; m < 2; ++m) a[m] = *(bf16x8_t*)&A[(mb + m * 16 + lr) * PITCH + klo];
#pragma unroll
      for (int n = 0; n < 4; ++n) {
        bg[n] = *(bf16x8_t*)&B[(n * 16 + lr) * PITCH + klo];
        bu[n] = *(bf16x8_t*)&B[((64 + n * 16) + lr) * PITCH + klo];
      }
#pragma unroll
      for (int m = 0; m < 2; ++m)
#pragma unroll
        for (int n = 0; n < 4; ++n) {
          accg[m][n] = __builtin_amdgcn_mfma_f32_16x16x32_bf16(a[m], bg[n], accg[m][n], 0, 0, 0);
          accu[m][n] = __builtin_amdgcn_mfma_f32_16x16x32_bf16(a[m], bu[n], accu[m][n], 0, 0, 0);
        }
    }
  }
#undef G1_ISSUE

  int mb = wv * 32, lr = lane & 15, rq = (lane >> 4) * 4;
#pragma unroll
  for (int m = 0; m < 2; ++m)
#pragma unroll
    for (int n = 0; n < 4; ++n)
#pragma unroll
      for (int j = 0; j < 4; ++j) {
        int r = tb + mb + m * 16 + rq + j;
        if (r < cnt) {
          float g = accg[m][n][j], u = accu[m][n][j];
          float hv = (g / (1.f + __expf(-g))) * u;
          hbuf[(size_t)(off + r) * ID + c0 + n * 16 + lr] = f2bf(hv);
        }
      }
}

// ---------------- gemm2: out = h @ Wd ----------------
__global__ __launch_bounds__(256) void k_gemm2(
    const unsigned short* __restrict__ hbuf, const float* __restrict__ dwn,
    const int* __restrict__ offsets, const int* __restrict__ tlist,
    const int* __restrict__ wk, float* __restrict__ out) {
  int item = blockIdx.y;
  if (item >= wk[MAXITEMS]) return;
  int w = wk[item];
  int e = w & 255, tb = (w >> 8) * 128;
  int off = offsets[e], cnt = offsets[e + 1] - off;
  int c0 = blockIdx.x * 128;

  __shared__ unsigned short lA[2][128 * PITCH];
  __shared__ unsigned short lB[2][128 * PITCH];

  int tid = threadIdx.x, lane = tid & 63, wv = tid >> 6;

  const float* Wd = dwn + (size_t)e * ID * HD;

  int rowA[4], octA[4], colB[4], koctB[4];
  const unsigned short* aP[4];
  const float* bP[4];
#pragma unroll
  for (int it = 0; it < 4; ++it) {
    int id = tid + 256 * it;
    rowA[it] = id >> 3; octA[it] = id & 7;
    int r = tb + rowA[it]; if (r > cnt - 1) r = cnt - 1;
    aP[it] = hbuf + (size_t)(off + r) * ID + octA[it] * 8;
    int col = id & 127, koct = id >> 7;
    colB[it] = col; koctB[it] = koct;
    bP[it] = Wd + (size_t)koct * 8 * HD + c0 + col;
  }

  uint4 aR[4];
  float bR[4][8];

#define G2_ISSUE() do { \
  _Pragma("unroll") for (int it = 0; it < 4; ++it) { aR[it] = *(const uint4*)aP[it]; aP[it] += 64; } \
  _Pragma("unroll") for (int it = 0; it < 4; ++it) { \
    const float* s = bP[it]; \
    _Pragma("unroll") for (int j = 0; j < 8; ++j) bR[it][j] = s[(size_t)j * HD]; \
    bP[it] += (size_t)64 * HD; } \
} while (0)

  G2_ISSUE();

  f32x4_t zero = {0.f, 0.f, 0.f, 0.f};
  f32x4_t acc[2][8];
#pragma unroll
  for (int m = 0; m < 2; ++m)
#pragma unroll
    for (int n = 0; n < 8; ++n) acc[m][n] = zero;

  for (int kt = 0; kt < 8; ++kt) {
    unsigned short* A = &lA[kt & 1][0];
    unsigned short* B = &lB[kt & 1][0];
#pragma unroll
    for (int it = 0; it < 4; ++it)
      *(uint4*)&A[rowA[it] * PITCH + octA[it] * 8] = aR[it];
#pragma unroll
    for (int it = 0; it < 4; ++it) {
      uint4 pk;
      pk.x = (unsigned)f2bf(bR[it][0]) | ((unsigned)f2bf(bR[it][1]) << 16);
      pk.y = (unsigned)f2bf(bR[it][2]) | ((unsigned)f2bf(bR[it][3]) << 16);
      pk.z = (unsigned)f2bf(bR[it][4]) | ((unsigned)f2bf(bR[it][5]) << 16);
      pk.w = (unsigned)f2bf(bR[it][6]) | ((unsigned)f2bf(bR[it][7]) << 16);
      *(uint4*)&B[colB[it] * PITCH + koctB[it] * 8] = pk;
    }
    __syncthreads();
    if (kt < 7) G2_ISSUE();

    int mb = wv * 32, lr = lane & 15;
#pragma unroll
    for (int kk = 0; kk < 2; ++kk) {
      int klo = kk * 32 + 8 * (lane >> 4);
      bf16x8_t a[2], b[8];
#pragma unroll
      for (int m = 0; m < 2; ++m) a[m] = *(bf16x8_t*)&A[(mb + m * 16 + lr) * PITCH + klo];
#pragma unroll
      for (int n = 0; n < 8; ++n) b[n] = *(bf16x8_t*)&B[(n * 16 + lr) * PITCH + klo];
#pragma unroll
      for (int m = 0; m < 2; ++m)
#pragma unroll
        for (int n = 0; n < 8; ++n)
          acc[m][n] = __builtin_amdgcn_mfma_f32_16x16x32_bf16(a[m], b[n], acc[m][n], 0, 0, 0);
    }
  }
#undef G2_ISSUE

  int mb = wv * 32, lr = lane & 15, rq = (lane >> 4) * 4;
#pragma unroll
  for (int m = 0; m < 2; ++m)
#pragma unroll
    for (int n = 0; n < 8; ++n)
#pragma unroll
      for (int j = 0; j < 4; ++j) {
        int r = tb + mb + m * 16 + rq + j;
        if (r < cnt) {
          out[(size_t)tlist[off + r] * HD + c0 + n * 16 + lr] = acc[m][n][j];
        }
      }
}

extern "C" void kernel_launch(void* const* d_in, const int* in_sizes, int n_in,
                              void* d_out, int out_size, void* d_ws, size_t ws_size,
                              hipStream_t stream) {
  (void)in_sizes; (void)n_in; (void)out_size; (void)ws_size;
  const float* x   = (const float*)d_in[0];
  const int*   tok = (const int*)d_in[1];
  const float* mu  = (const float*)d_in[2];
  const float* gup = (const float*)d_in[3];
  const float* dwn = (const float*)d_in[4];
  const float* wr  = (const float*)d_in[5];
  float* out = (float*)d_out;

  char* ws = (char*)d_ws;
  int* eid     = (int*)ws;
  int* tlist   = (int*)(ws + 16384);
  int* counts  = (int*)(ws + 32768);
  int* offsets = (int*)(ws + 32896);
  int* cursors = (int*)(ws + 33024);
  int* wk      = (int*)(ws + 33152);
  unsigned short* xb   = (unsigned short*)(ws + 65536);
  unsigned short* hbuf = (unsigned short*)(ws + 65536 + (size_t)NT * HD * 2);

  k_cast_x <<<4096, 256, 0, stream>>>(x, xb);
  k_route  <<<NT, 256, 0, stream>>>(mu, tok, wr, eid);
  k_init   <<<1, 64, 0, stream>>>(counts, cursors);
  k_hist   <<<16, 256, 0, stream>>>(eid, counts);
  k_scan   <<<1, 64, 0, stream>>>(counts, offsets, cursors, wk);
  k_scatter<<<16, 256, 0, stream>>>(eid, cursors, tlist);
  k_gemm1  <<<dim3(8, MAXITEMS), 256, 0, stream>>>(xb, gup, offsets, tlist, wk, hbuf);
  k_gemm2  <<<dim3(16, MAXITEMS), 256, 0, stream>>>(hbuf, dwn, offsets, tlist, wk, out);
}

// Round 5
// 309.931 us; speedup vs baseline: 1.0029x; 1.0029x over previous
//
#include <hip/hip_runtime.h>
#include <hip/hip_bf16.h>

#define NT 4096
#define HD 2048
#define NE 16
#define ID 512
#define TWO_I 1024
#define PITCH 72   // LDS row pitch in ushorts (144B) -> dodges pow2 bank stride
#define MAXITEMS 47  // worst case: ceil(4081/128)=32 + 15 singleton experts

typedef __attribute__((ext_vector_type(8))) short bf16x8_t;
typedef __attribute__((ext_vector_type(4))) float f32x4_t;

__device__ __forceinline__ unsigned short f2bf(float f) {
  union { float f; unsigned int u; } v; v.f = f;
  unsigned int r = v.u + 0x7fffu + ((v.u >> 16) & 1u);
  return (unsigned short)(r >> 16);
}

// ---------------- cast x (f32 -> bf16), 8 elems/thread ----------------
__global__ void k_cast_x(const float* __restrict__ x, unsigned short* __restrict__ xb) {
  size_t i = ((size_t)blockIdx.x * 256 + threadIdx.x) * 8;
  float4 a = *(const float4*)(x + i);
  float4 b = *(const float4*)(x + i + 4);
  unsigned int w0 = (unsigned)f2bf(a.x) | ((unsigned)f2bf(a.y) << 16);
  unsigned int w1 = (unsigned)f2bf(a.z) | ((unsigned)f2bf(a.w) << 16);
  unsigned int w2 = (unsigned)f2bf(b.x) | ((unsigned)f2bf(b.y) << 16);
  unsigned int w3 = (unsigned)f2bf(b.z) | ((unsigned)f2bf(b.w) << 16);
  uint4 pk; pk.x = w0; pk.y = w1; pk.z = w2; pk.w = w3;
  *(uint4*)(xb + i) = pk;
}

// ---------------- routing ----------------
__global__ void k_route(const float* __restrict__ mu, const int* __restrict__ tok,
                        const float* __restrict__ wr, int* __restrict__ eid) {
  int t = blockIdx.x;
  int tid = threadIdx.x;
  float p[NE];
#pragma unroll
  for (int e = 0; e < NE; ++e) p[e] = 0.f;
  const float* m = mu + (size_t)t * HD;
  for (int h = tid; h < HD; h += 256) {
    float mv = m[h];
#pragma unroll
    for (int e = 0; e < NE; ++e) p[e] += mv * wr[e * HD + h];
  }
#pragma unroll
  for (int e = 0; e < NE; ++e) {
    float v = p[e];
#pragma unroll
    for (int s = 32; s; s >>= 1) v += __shfl_xor(v, s, 64);
    p[e] = v;
  }
  __shared__ float red[4][NE];
  int lane = tid & 63, wv = tid >> 6;
  if (lane == 0) {
#pragma unroll
    for (int e = 0; e < NE; ++e) red[wv][e] = p[e];
  }
  __syncthreads();
  if (tid == 0) {
    int tk = tok[t];
    if (tk < 0) tk = 0;
    if (tk > 31999) tk = 31999;
    int base = tk & 15;
    float best = -3.0e38f; int bi = 0;
    for (int e = 0; e < NE; ++e) {
      float v = red[0][e] + red[1][e] + red[2][e] + red[3][e];
      if (e == base) v += 10.0f;
      if (v > best) { best = v; bi = e; }
    }
    eid[t] = bi;
  }
}

// ---------------- bucket tokens by expert + build compacted worklist ----------------
__global__ void k_init(int* counts, int* cursors) {
  int i = threadIdx.x;
  if (i < NE) { counts[i] = 0; cursors[i] = 0; }
}
__global__ void k_hist(const int* __restrict__ eid, int* __restrict__ counts) {
  int t = blockIdx.x * 256 + threadIdx.x;
  if (t < NT) atomicAdd(&counts[eid[t]], 1);
}
__global__ void k_scan(const int* __restrict__ counts, int* __restrict__ offsets,
                       int* __restrict__ cursors, int* __restrict__ wk) {
  if (threadIdx.x == 0) {
    int s = 0;
    for (int e = 0; e < NE; ++e) { offsets[e] = s; cursors[e] = s; s += counts[e]; }
    offsets[NE] = s;
    int n = 0;
    for (int e = 0; e < NE; ++e) {
      int tiles = (counts[e] + 127) >> 7;
      for (int m = 0; m < tiles; ++m) { wk[n++] = e | (m << 8); }
    }
    wk[MAXITEMS] = n;
  }
}
__global__ void k_scatter(const int* __restrict__ eid, int* __restrict__ cursors,
                          int* __restrict__ tlist) {
  int t = blockIdx.x * 256 + threadIdx.x;
  if (t < NT) {
    int e = eid[t];
    int pos = atomicAdd(&cursors[e], 1);
    tlist[pos] = t;
  }
}

// ---------------- gemm1: h = silu(x@Wg) * (x@Wu) ----------------
// dbuf LDS; loads for step k+1 issued AFTER the barrier so they fly under MFMA(k)
// (256,1): min 1 wave/EU -> up to 512 unified VGPRs, no spills of the prefetch regs
__global__ __launch_bounds__(256, 1) void k_gemm1(
    const unsigned short* __restrict__ xb, const float* __restrict__ gup,
    const int* __restrict__ offsets, const int* __restrict__ tlist,
    const int* __restrict__ wk, unsigned short* __restrict__ hbuf) {
  int item = blockIdx.y;
  if (item >= wk[MAXITEMS]) return;
  int w = wk[item];
  int e = w & 255, tb = (w >> 8) * 128;
  int off = offsets[e], cnt = offsets[e + 1] - off;
  int c0 = blockIdx.x * 64;

  __shared__ unsigned short lA[2][128 * PITCH];
  __shared__ unsigned short lB[2][128 * PITCH];
  __shared__ int ltok[128];

  int tid = threadIdx.x, lane = tid & 63, wv = tid >> 6;
  if (tid < 128) {
    int r = tb + tid; if (r > cnt - 1) r = cnt - 1;
    ltok[tid] = tlist[off + r];
  }
  __syncthreads();

  const float* Wg = gup + (size_t)e * HD * TWO_I;

  int rowA[4], octA[4], colB[4], koctB[4];
  const unsigned short* aP[4];
  const float* bP[4];
#pragma unroll
  for (int it = 0; it < 4; ++it) {
    int id = tid + 256 * it;
    rowA[it] = id >> 3; octA[it] = id & 7;
    aP[it] = xb + (size_t)ltok[rowA[it]] * HD + octA[it] * 8;
    int col = id & 127, koct = id >> 7;
    colB[it] = col; koctB[it] = koct;
    int gcol = (col < 64) ? (c0 + col) : (ID + c0 + (col - 64));
    bP[it] = Wg + (size_t)koct * 8 * TWO_I + gcol;
  }

  uint4 aR[4];
  float bR[4][8];

#define G1_ISSUE() do { \
  _Pragma("unroll") for (int it = 0; it < 4; ++it) { aR[it] = *(const uint4*)aP[it]; aP[it] += 64; } \
  _Pragma("unroll") for (int it = 0; it < 4; ++it) { \
    const float* s = bP[it]; \
    _Pragma("unroll") for (int j = 0; j < 8; ++j) bR[it][j] = s[(size_t)j * TWO_I]; \
    bP[it] += (size_t)64 * TWO_I; } \
} while (0)

  G1_ISSUE();

  f32x4_t zero = {0.f, 0.f, 0.f, 0.f};
  f32x4_t accg[2][4], accu[2][4];
#pragma unroll
  for (int m = 0; m < 2; ++m)
#pragma unroll
    for (int n = 0; n < 4; ++n) { accg[m][n] = zero; accu[m][n] = zero; }

  for (int kt = 0; kt < 32; ++kt) {
    unsigned short* A = &lA[kt & 1][0];
    unsigned short* B = &lB[kt & 1][0];
#pragma unroll
    for (int it = 0; it < 4; ++it)
      *(uint4*)&A[rowA[it] * PITCH + octA[it] * 8] = aR[it];
#pragma unroll
    for (int it = 0; it < 4; ++it) {
      uint4 pk;
      pk.x = (unsigned)f2bf(bR[it][0]) | ((unsigned)f2bf(bR[it][1]) << 16);
      pk.y = (unsigned)f2bf(bR[it][2]) | ((unsigned)f2bf(bR[it][3]) << 16);
      pk.z = (unsigned)f2bf(bR[it][4]) | ((unsigned)f2bf(bR[it][5]) << 16);
      pk.w = (unsigned)f2bf(bR[it][6]) | ((unsigned)f2bf(bR[it][7]) << 16);
      *(uint4*)&B[colB[it] * PITCH + koctB[it] * 8] = pk;
    }
    __syncthreads();
    if (kt < 31) G1_ISSUE();   // issue AFTER barrier: loads fly under MFMA phase

    int mb = wv * 32, lr = lane & 15;
#pragma unroll
    for (int kk = 0; kk < 2; ++kk) {
      int klo = kk * 32 + 8 * (lane >> 4);
      bf16x8_t a[2], bg[4], bu[4];
#pragma unroll
      for (int m = 0; m < 2; ++m) a[m] = *(bf16x8_t*)&A[(mb + m * 16 + lr) * PITCH + klo];
#pragma unroll
      for (int n = 0; n < 4; ++n) {
        bg[n] = *(bf16x8_t*)&B[(n * 16 + lr) * PITCH + klo];
        bu[n] = *(bf16x8_t*)&B[((64 + n * 16) + lr) * PITCH + klo];
      }
#pragma unroll
      for (int m = 0; m < 2; ++m)
#pragma unroll
        for (int n = 0; n < 4; ++n) {
          accg[m][n] = __builtin_amdgcn_mfma_f32_16x16x32_bf16(a[m], bg[n], accg[m][n], 0, 0, 0);
          accu[m][n] = __builtin_amdgcn_mfma_f32_16x16x32_bf16(a[m], bu[n], accu[m][n], 0, 0, 0);
        }
    }
  }
#undef G1_ISSUE

  int mb = wv * 32, lr = lane & 15, rq = (lane >> 4) * 4;
#pragma unroll
  for (int m = 0; m < 2; ++m)
#pragma unroll
    for (int n = 0; n < 4; ++n)
#pragma unroll
      for (int j = 0; j < 4; ++j) {
        int r = tb + mb + m * 16 + rq + j;
        if (r < cnt) {
          float g = accg[m][n][j], u = accu[m][n][j];
          float hv = (g / (1.f + __expf(-g))) * u;
          hbuf[(size_t)(off + r) * ID + c0 + n * 16 + lr] = f2bf(hv);
        }
      }
}

// ---------------- gemm2: out = h @ Wd ----------------
__global__ __launch_bounds__(256, 1) void k_gemm2(
    const unsigned short* __restrict__ hbuf, const float* __restrict__ dwn,
    const int* __restrict__ offsets, const int* __restrict__ tlist,
    const int* __restrict__ wk, float* __restrict__ out) {
  int item = blockIdx.y;
  if (item >= wk[MAXITEMS]) return;
  int w = wk[item];
  int e = w & 255, tb = (w >> 8) * 128;
  int off = offsets[e], cnt = offsets[e + 1] - off;
  int c0 = blockIdx.x * 128;

  __shared__ unsigned short lA[2][128 * PITCH];
  __shared__ unsigned short lB[2][128 * PITCH];

  int tid = threadIdx.x, lane = tid & 63, wv = tid >> 6;

  const float* Wd = dwn + (size_t)e * ID * HD;

  int rowA[4], octA[4], colB[4], koctB[4];
  const unsigned short* aP[4];
  const float* bP[4];
#pragma unroll
  for (int it = 0; it < 4; ++it) {
    int id = tid + 256 * it;
    rowA[it] = id >> 3; octA[it] = id & 7;
    int r = tb + rowA[it]; if (r > cnt - 1) r = cnt - 1;
    aP[it] = hbuf + (size_t)(off + r) * ID + octA[it] * 8;
    int col = id & 127, koct = id >> 7;
    colB[it] = col; koctB[it] = koct;
    bP[it] = Wd + (size_t)koct * 8 * HD + c0 + col;
  }

  uint4 aR[4];
  float bR[4][8];

#define G2_ISSUE() do { \
  _Pragma("unroll") for (int it = 0; it < 4; ++it) { aR[it] = *(const uint4*)aP[it]; aP[it] += 64; } \
  _Pragma("unroll") for (int it = 0; it < 4; ++it) { \
    const float* s = bP[it]; \
    _Pragma("unroll") for (int j = 0; j < 8; ++j) bR[it][j] = s[(size_t)j * HD]; \
    bP[it] += (size_t)64 * HD; } \
} while (0)

  G2_ISSUE();

  f32x4_t zero = {0.f, 0.f, 0.f, 0.f};
  f32x4_t acc[2][8];
#pragma unroll
  for (int m = 0; m < 2; ++m)
#pragma unroll
    for (int n = 0; n < 8; ++n) acc[m][n] = zero;

  for (int kt = 0; kt < 8; ++kt) {
    unsigned short* A = &lA[kt & 1][0];
    unsigned short* B = &lB[kt & 1][0];
#pragma unroll
    for (int it = 0; it < 4; ++it)
      *(uint4*)&A[rowA[it] * PITCH + octA[it] * 8] = aR[it];
#pragma unroll
    for (int it = 0; it < 4; ++it) {
      uint4 pk;
      pk.x = (unsigned)f2bf(bR[it][0]) | ((unsigned)f2bf(bR[it][1]) << 16);
      pk.y = (unsigned)f2bf(bR[it][2]) | ((unsigned)f2bf(bR[it][3]) << 16);
      pk.z = (unsigned)f2bf(bR[it][4]) | ((unsigned)f2bf(bR[it][5]) << 16);
      pk.w = (unsigned)f2bf(bR[it][6]) | ((unsigned)f2bf(bR[it][7]) << 16);
      *(uint4*)&B[colB[it] * PITCH + koctB[it] * 8] = pk;
    }
    __syncthreads();
    if (kt < 7) G2_ISSUE();

    int mb = wv * 32, lr = lane & 15;
#pragma unroll
    for (int kk = 0; kk < 2; ++kk) {
      int klo = kk * 32 + 8 * (lane >> 4);
      bf16x8_t a[2], b[8];
#pragma unroll
      for (int m = 0; m < 2; ++m) a[m] = *(bf16x8_t*)&A[(mb + m * 16 + lr) * PITCH + klo];
#pragma unroll
      for (int n = 0; n < 8; ++n) b[n] = *(bf16x8_t*)&B[(n * 16 + lr) * PITCH + klo];
#pragma unroll
      for (int m = 0; m < 2; ++m)
#pragma unroll
        for (int n = 0; n < 8; ++n)
          acc[m][n] = __builtin_amdgcn_mfma_f32_16x16x32_bf16(a[m], b[n], acc[m][n], 0, 0, 0);
    }
  }
#undef G2_ISSUE

  int mb = wv * 32, lr = lane & 15, rq = (lane >> 4) * 4;
#pragma unroll
  for (int m = 0; m < 2; ++m)
#pragma unroll
    for (int n = 0; n < 8; ++n)
#pragma unroll
      for (int j = 0; j < 4; ++j) {
        int r = tb + mb + m * 16 + rq + j;
        if (r < cnt) {
          out[(size_t)tlist[off + r] * HD + c0 + n * 16 + lr] = acc[m][n][j];
        }
      }
}

extern "C" void kernel_launch(void* const* d_in, const int* in_sizes, int n_in,
                              void* d_out, int out_size, void* d_ws, size_t ws_size,
                              hipStream_t stream) {
  (void)in_sizes; (void)n_in; (void)out_size; (void)ws_size;
  const float* x   = (const float*)d_in[0];
  const int*   tok = (const int*)d_in[1];
  const float* mu  = (const float*)d_in[2];
  const float* gup = (const float*)d_in[3];
  const float* dwn = (const float*)d_in[4];
  const float* wr  = (const float*)d_in[5];
  float* out = (float*)d_out;

  char* ws = (char*)d_ws;
  int* eid     = (int*)ws;
  int* tlist   = (int*)(ws + 16384);
  int* counts  = (int*)(ws + 32768);
  int* offsets = (int*)(ws + 32896);
  int* cursors = (int*)(ws + 33024);
  int* wk      = (int*)(ws + 33152);
  unsigned short* xb   = (unsigned short*)(ws + 65536);
  unsigned short* hbuf = (unsigned short*)(ws + 65536 + (size_t)NT * HD * 2);

  k_cast_x <<<4096, 256, 0, stream>>>(x, xb);
  k_route  <<<NT, 256, 0, stream>>>(mu, tok, wr, eid);
  k_init   <<<1, 64, 0, stream>>>(counts, cursors);
  k_hist   <<<16, 256, 0, stream>>>(eid, counts);
  k_scan   <<<1, 64, 0, stream>>>(counts, offsets, cursors, wk);
  k_scatter<<<16, 256, 0, stream>>>(eid, cursors, tlist);
  k_gemm1  <<<dim3(8, MAXITEMS), 256, 0, stream>>>(xb, gup, offsets, tlist, wk, hbuf);
  k_gemm2  <<<dim3(16, MAXITEMS), 256, 0, stream>>>(hbuf, dwn, offsets, tlist, wk, out);
}

// Round 6
// 188.275 us; speedup vs baseline: 1.6509x; 1.6462x over previous
//
#include <hip/hip_runtime.h>
#include <hip/hip_bf16.h>

#define NT 4096
#define HD 2048
#define NE 16
#define ID 512
#define TWO_I 1024
#define PITCH 72   // LDS row pitch in ushorts (144B) -> dodges pow2 bank stride
#define MAXITEMS 47  // worst case: ceil(4081/128)=32 + 15 singleton experts

typedef __attribute__((ext_vector_type(8))) short bf16x8_t;
typedef __attribute__((ext_vector_type(4))) float f32x4_t;

__device__ __forceinline__ unsigned short f2bf(float f) {
  union { float f; unsigned int u; } v; v.f = f;
  unsigned int r = v.u + 0x7fffu + ((v.u >> 16) & 1u);
  return (unsigned short)(r >> 16);
}

// ---------------- cast x (f32 -> bf16), 8 elems/thread ----------------
__global__ void k_cast_x(const float* __restrict__ x, unsigned short* __restrict__ xb) {
  size_t i = ((size_t)blockIdx.x * 256 + threadIdx.x) * 8;
  float4 a = *(const float4*)(x + i);
  float4 b = *(const float4*)(x + i + 4);
  unsigned int w0 = (unsigned)f2bf(a.x) | ((unsigned)f2bf(a.y) << 16);
  unsigned int w1 = (unsigned)f2bf(a.z) | ((unsigned)f2bf(a.w) << 16);
  unsigned int w2 = (unsigned)f2bf(b.x) | ((unsigned)f2bf(b.y) << 16);
  unsigned int w3 = (unsigned)f2bf(b.z) | ((unsigned)f2bf(b.w) << 16);
  uint4 pk; pk.x = w0; pk.y = w1; pk.z = w2; pk.w = w3;
  *(uint4*)(xb + i) = pk;
}

// ---------------- routing ----------------
__global__ void k_route(const float* __restrict__ mu, const int* __restrict__ tok,
                        const float* __restrict__ wr, int* __restrict__ eid) {
  int t = blockIdx.x;
  int tid = threadIdx.x;
  float p[NE];
#pragma unroll
  for (int e = 0; e < NE; ++e) p[e] = 0.f;
  const float* m = mu + (size_t)t * HD;
  for (int h = tid; h < HD; h += 256) {
    float mv = m[h];
#pragma unroll
    for (int e = 0; e < NE; ++e) p[e] += mv * wr[e * HD + h];
  }
#pragma unroll
  for (int e = 0; e < NE; ++e) {
    float v = p[e];
#pragma unroll
    for (int s = 32; s; s >>= 1) v += __shfl_xor(v, s, 64);
    p[e] = v;
  }
  __shared__ float red[4][NE];
  int lane = tid & 63, wv = tid >> 6;
  if (lane == 0) {
#pragma unroll
    for (int e = 0; e < NE; ++e) red[wv][e] = p[e];
  }
  __syncthreads();
  if (tid == 0) {
    int tk = tok[t];
    if (tk < 0) tk = 0;
    if (tk > 31999) tk = 31999;
    int base = tk & 15;
    float best = -3.0e38f; int bi = 0;
    for (int e = 0; e < NE; ++e) {
      float v = red[0][e] + red[1][e] + red[2][e] + red[3][e];
      if (e == base) v += 10.0f;
      if (v > best) { best = v; bi = e; }
    }
    eid[t] = bi;
  }
}

// ---------------- bucket tokens by expert + build compacted worklist ----------------
__global__ void k_init(int* counts, int* cursors) {
  int i = threadIdx.x;
  if (i < NE) { counts[i] = 0; cursors[i] = 0; }
}
__global__ void k_hist(const int* __restrict__ eid, int* __restrict__ counts) {
  int t = blockIdx.x * 256 + threadIdx.x;
  if (t < NT) atomicAdd(&counts[eid[t]], 1);
}
__global__ void k_scan(const int* __restrict__ counts, int* __restrict__ offsets,
                       int* __restrict__ cursors, int* __restrict__ wk) {
  if (threadIdx.x == 0) {
    int s = 0;
    for (int e = 0; e < NE; ++e) { offsets[e] = s; cursors[e] = s; s += counts[e]; }
    offsets[NE] = s;
    int n = 0;
    for (int e = 0; e < NE; ++e) {
      int tiles = (counts[e] + 127) >> 7;
      for (int m = 0; m < tiles; ++m) { wk[n++] = e | (m << 8); }
    }
    wk[MAXITEMS] = n;
  }
}
__global__ void k_scatter(const int* __restrict__ eid, int* __restrict__ cursors,
                          int* __restrict__ tlist) {
  int t = blockIdx.x * 256 + threadIdx.x;
  if (t < NT) {
    int e = eid[t];
    int pos = atomicAdd(&cursors[e], 1);
    tlist[pos] = t;
  }
}

// ---------------- gemm1: h = silu(x@Wg) * (x@Wu) ----------------
// write-through staging (no long-lived prefetch arrays), single-buffer LDS,
// small tiles (M=128, 32 gate + 32 up cols) -> ~544 blocks, TLP hides latency.
__global__ __launch_bounds__(256, 3) void k_gemm1(
    const unsigned short* __restrict__ xb, const float* __restrict__ gup,
    const int* __restrict__ offsets, const int* __restrict__ tlist,
    const int* __restrict__ wk, unsigned short* __restrict__ hbuf) {
  int item = blockIdx.y;
  if (item >= wk[MAXITEMS]) return;
  int w = wk[item];
  int e = w & 255, tb = (w >> 8) * 128;
  int off = offsets[e], cnt = offsets[e + 1] - off;
  int c0 = blockIdx.x * 32;   // 16 col-tiles cover ID=512

  __shared__ unsigned short lA[128 * PITCH];  // [token][k] bf16
  __shared__ unsigned short lB[64 * PITCH];   // rows 0-31 gate, 32-63 up
  __shared__ int ltok[128];

  int tid = threadIdx.x, lane = tid & 63, wv = tid >> 6;
  if (tid < 128) {
    int r = tb + tid; if (r > cnt - 1) r = cnt - 1;
    ltok[tid] = tlist[off + r];
  }
  __syncthreads();

  const float* Wg = gup + (size_t)e * HD * TWO_I;

  // A: 4 items/thread (1024 items of 16B)
  const unsigned short* aP[4];
  unsigned aL[4];
#pragma unroll
  for (int it = 0; it < 4; ++it) {
    int id = tid + 256 * it;
    int row = id >> 3, oct = id & 7;
    aP[it] = xb + (size_t)ltok[row] * HD + oct * 8;
    aL[it] = row * PITCH + oct * 8;
  }
  // B: 2 items/thread (512 items: col(32) x grp(2) x koct(8))
  const float* bP[2];
  unsigned bL[2];
#pragma unroll
  for (int it = 0; it < 2; ++it) {
    int id = tid + 256 * it;
    int col = id & 31, grp = (id >> 5) & 1, koct = id >> 6;
    int gcol = grp ? (ID + c0 + col) : (c0 + col);
    bP[it] = Wg + (size_t)koct * 8 * TWO_I + gcol;
    bL[it] = (grp * 32 + col) * PITCH + koct * 8;
  }

  f32x4_t zero = {0.f, 0.f, 0.f, 0.f};
  f32x4_t accg[2][2], accu[2][2];
#pragma unroll
  for (int m = 0; m < 2; ++m)
#pragma unroll
    for (int n = 0; n < 2; ++n) { accg[m][n] = zero; accu[m][n] = zero; }

  for (int kt = 0; kt < 32; ++kt) {
    // issue all loads for this K-step (short-lived regs)
    uint4 a0 = *(const uint4*)aP[0], a1 = *(const uint4*)aP[1];
    uint4 a2 = *(const uint4*)aP[2], a3 = *(const uint4*)aP[3];
    float b0[8], b1[8];
#pragma unroll
    for (int j = 0; j < 8; ++j) b0[j] = bP[0][(size_t)j * TWO_I];
#pragma unroll
    for (int j = 0; j < 8; ++j) b1[j] = bP[1][(size_t)j * TWO_I];
#pragma unroll
    for (int it = 0; it < 4; ++it) aP[it] += 64;
#pragma unroll
    for (int it = 0; it < 2; ++it) bP[it] += (size_t)64 * TWO_I;

    __syncthreads();   // previous MFMA reads complete
    *(uint4*)&lA[aL[0]] = a0; *(uint4*)&lA[aL[1]] = a1;
    *(uint4*)&lA[aL[2]] = a2; *(uint4*)&lA[aL[3]] = a3;
    uint4 p0, p1;
    p0.x = (unsigned)f2bf(b0[0]) | ((unsigned)f2bf(b0[1]) << 16);
    p0.y = (unsigned)f2bf(b0[2]) | ((unsigned)f2bf(b0[3]) << 16);
    p0.z = (unsigned)f2bf(b0[4]) | ((unsigned)f2bf(b0[5]) << 16);
    p0.w = (unsigned)f2bf(b0[6]) | ((unsigned)f2bf(b0[7]) << 16);
    p1.x = (unsigned)f2bf(b1[0]) | ((unsigned)f2bf(b1[1]) << 16);
    p1.y = (unsigned)f2bf(b1[2]) | ((unsigned)f2bf(b1[3]) << 16);
    p1.z = (unsigned)f2bf(b1[4]) | ((unsigned)f2bf(b1[5]) << 16);
    p1.w = (unsigned)f2bf(b1[6]) | ((unsigned)f2bf(b1[7]) << 16);
    *(uint4*)&lB[bL[0]] = p0; *(uint4*)&lB[bL[1]] = p1;
    __syncthreads();   // tile ready

    int mb = wv * 32, lr = lane & 15;
#pragma unroll
    for (int kk = 0; kk < 2; ++kk) {
      int klo = kk * 32 + 8 * (lane >> 4);
      bf16x8_t a[2], bg[2], bu[2];
#pragma unroll
      for (int m = 0; m < 2; ++m) a[m] = *(bf16x8_t*)&lA[(mb + m * 16 + lr) * PITCH + klo];
#pragma unroll
      for (int n = 0; n < 2; ++n) {
        bg[n] = *(bf16x8_t*)&lB[(n * 16 + lr) * PITCH + klo];
        bu[n] = *(bf16x8_t*)&lB[((32 + n * 16) + lr) * PITCH + klo];
      }
#pragma unroll
      for (int m = 0; m < 2; ++m)
#pragma unroll
        for (int n = 0; n < 2; ++n) {
          accg[m][n] = __builtin_amdgcn_mfma_f32_16x16x32_bf16(a[m], bg[n], accg[m][n], 0, 0, 0);
          accu[m][n] = __builtin_amdgcn_mfma_f32_16x16x32_bf16(a[m], bu[n], accu[m][n], 0, 0, 0);
        }
    }
  }

  int mb = wv * 32, lr = lane & 15, rq = (lane >> 4) * 4;
#pragma unroll
  for (int m = 0; m < 2; ++m)
#pragma unroll
    for (int n = 0; n < 2; ++n)
#pragma unroll
      for (int j = 0; j < 4; ++j) {
        int r = tb + mb + m * 16 + rq + j;
        if (r < cnt) {
          float g = accg[m][n][j], u = accu[m][n][j];
          float hv = (g / (1.f + __expf(-g))) * u;
          hbuf[(size_t)(off + r) * ID + c0 + n * 16 + lr] = f2bf(hv);
        }
      }
}

// ---------------- gemm2: out = h @ Wd ----------------
// same write-through structure; M=128 x 64 out-cols, grid 32 x items
__global__ __launch_bounds__(256, 3) void k_gemm2(
    const unsigned short* __restrict__ hbuf, const float* __restrict__ dwn,
    const int* __restrict__ offsets, const int* __restrict__ tlist,
    const int* __restrict__ wk, float* __restrict__ out) {
  int item = blockIdx.y;
  if (item >= wk[MAXITEMS]) return;
  int w = wk[item];
  int e = w & 255, tb = (w >> 8) * 128;
  int off = offsets[e], cnt = offsets[e + 1] - off;
  int c0 = blockIdx.x * 64;   // 32 col-tiles cover HD=2048

  __shared__ unsigned short lA[128 * PITCH];
  __shared__ unsigned short lB[64 * PITCH];

  int tid = threadIdx.x, lane = tid & 63, wv = tid >> 6;

  const float* Wd = dwn + (size_t)e * ID * HD;

  const unsigned short* aP[4];
  unsigned aL[4];
#pragma unroll
  for (int it = 0; it < 4; ++it) {
    int id = tid + 256 * it;
    int row = id >> 3, oct = id & 7;
    int r = tb + row; if (r > cnt - 1) r = cnt - 1;
    aP[it] = hbuf + (size_t)(off + r) * ID + oct * 8;
    aL[it] = row * PITCH + oct * 8;
  }
  const float* bP[2];
  unsigned bL[2];
#pragma unroll
  for (int it = 0; it < 2; ++it) {
    int id = tid + 256 * it;
    int col = id & 63, koct = id >> 6;
    bP[it] = Wd + (size_t)koct * 8 * HD + c0 + col;
    bL[it] = col * PITCH + koct * 8;
  }

  f32x4_t zero = {0.f, 0.f, 0.f, 0.f};
  f32x4_t acc[2][4];
#pragma unroll
  for (int m = 0; m < 2; ++m)
#pragma unroll
    for (int n = 0; n < 4; ++n) acc[m][n] = zero;

  for (int kt = 0; kt < 8; ++kt) {
    uint4 a0 = *(const uint4*)aP[0], a1 = *(const uint4*)aP[1];
    uint4 a2 = *(const uint4*)aP[2], a3 = *(const uint4*)aP[3];
    float b0[8], b1[8];
#pragma unroll
    for (int j = 0; j < 8; ++j) b0[j] = bP[0][(size_t)j * HD];
#pragma unroll
    for (int j = 0; j < 8; ++j) b1[j] = bP[1][(size_t)j * HD];
#pragma unroll
    for (int it = 0; it < 4; ++it) aP[it] += 64;
#pragma unroll
    for (int it = 0; it < 2; ++it) bP[it] += (size_t)64 * HD;

    __syncthreads();
    *(uint4*)&lA[aL[0]] = a0; *(uint4*)&lA[aL[1]] = a1;
    *(uint4*)&lA[aL[2]] = a2; *(uint4*)&lA[aL[3]] = a3;
    uint4 p0, p1;
    p0.x = (unsigned)f2bf(b0[0]) | ((unsigned)f2bf(b0[1]) << 16);
    p0.y = (unsigned)f2bf(b0[2]) | ((unsigned)f2bf(b0[3]) << 16);
    p0.z = (unsigned)f2bf(b0[4]) | ((unsigned)f2bf(b0[5]) << 16);
    p0.w = (unsigned)f2bf(b0[6]) | ((unsigned)f2bf(b0[7]) << 16);
    p1.x = (unsigned)f2bf(b1[0]) | ((unsigned)f2bf(b1[1]) << 16);
    p1.y = (unsigned)f2bf(b1[2]) | ((unsigned)f2bf(b1[3]) << 16);
    p1.z = (unsigned)f2bf(b1[4]) | ((unsigned)f2bf(b1[5]) << 16);
    p1.w = (unsigned)f2bf(b1[6]) | ((unsigned)f2bf(b1[7]) << 16);
    *(uint4*)&lB[bL[0]] = p0; *(uint4*)&lB[bL[1]] = p1;
    __syncthreads();

    int mb = wv * 32, lr = lane & 15;
#pragma unroll
    for (int kk = 0; kk < 2; ++kk) {
      int klo = kk * 32 + 8 * (lane >> 4);
      bf16x8_t a[2], b[4];
#pragma unroll
      for (int m = 0; m < 2; ++m) a[m] = *(bf16x8_t*)&lA[(mb + m * 16 + lr) * PITCH + klo];
#pragma unroll
      for (int n = 0; n < 4; ++n) b[n] = *(bf16x8_t*)&lB[(n * 16 + lr) * PITCH + klo];
#pragma unroll
      for (int m = 0; m < 2; ++m)
#pragma unroll
        for (int n = 0; n < 4; ++n)
          acc[m][n] = __builtin_amdgcn_mfma_f32_16x16x32_bf16(a[m], b[n], acc[m][n], 0, 0, 0);
    }
  }

  int mb = wv * 32, lr = lane & 15, rq = (lane >> 4) * 4;
#pragma unroll
  for (int m = 0; m < 2; ++m)
#pragma unroll
    for (int n = 0; n < 4; ++n)
#pragma unroll
      for (int j = 0; j < 4; ++j) {
        int r = tb + mb + m * 16 + rq + j;
        if (r < cnt) {
          out[(size_t)tlist[off + r] * HD + c0 + n * 16 + lr] = acc[m][n][j];
        }
      }
}

extern "C" void kernel_launch(void* const* d_in, const int* in_sizes, int n_in,
                              void* d_out, int out_size, void* d_ws, size_t ws_size,
                              hipStream_t stream) {
  (void)in_sizes; (void)n_in; (void)out_size; (void)ws_size;
  const float* x   = (const float*)d_in[0];
  const int*   tok = (const int*)d_in[1];
  const float* mu  = (const float*)d_in[2];
  const float* gup = (const float*)d_in[3];
  const float* dwn = (const float*)d_in[4];
  const float* wr  = (const float*)d_in[5];
  float* out = (float*)d_out;

  char* ws = (char*)d_ws;
  int* eid     = (int*)ws;
  int* tlist   = (int*)(ws + 16384);
  int* counts  = (int*)(ws + 32768);
  int* offsets = (int*)(ws + 32896);
  int* cursors = (int*)(ws + 33024);
  int* wk      = (int*)(ws + 33152);
  unsigned short* xb   = (unsigned short*)(ws + 65536);
  unsigned short* hbuf = (unsigned short*)(ws + 65536 + (size_t)NT * HD * 2);

  k_cast_x <<<4096, 256, 0, stream>>>(x, xb);
  k_route  <<<NT, 256, 0, stream>>>(mu, tok, wr, eid);
  k_init   <<<1, 64, 0, stream>>>(counts, cursors);
  k_hist   <<<16, 256, 0, stream>>>(eid, counts);
  k_scan   <<<1, 64, 0, stream>>>(counts, offsets, cursors, wk);
  k_scatter<<<16, 256, 0, stream>>>(eid, cursors, tlist);
  k_gemm1  <<<dim3(16, MAXITEMS), 256, 0, stream>>>(xb, gup, offsets, tlist, wk, hbuf);
  k_gemm2  <<<dim3(32, MAXITEMS), 256, 0, stream>>>(hbuf, dwn, offsets, tlist, wk, out);
}